// Round 4
// baseline (987.170 us; speedup 1.0000x reference)
//
#include <hip/hip_runtime.h>
#include <hip/hip_bf16.h>
#include <cstdint>
#include <cstddef>

typedef int v4i __attribute__((ext_vector_type(4)));

#define NH 32
#define HD 128
#define SEQ 1024
#define HID 4096
#define BB 2

__device__ __forceinline__ signed char quant_i8(float x) {
    float r = rintf(x);                       // round-half-to-even, matches jnp.round
    r = fminf(fmaxf(r, -128.0f), 127.0f);
    return (signed char)r;
}

#define GLOAD_LDS16(g, l) \
    __builtin_amdgcn_global_load_lds((const __attribute__((address_space(1))) void*)(g), \
                                     (__attribute__((address_space(3))) void*)(l), 16, 0, 0)

// ---------------- pack int32 -> int8 in MFMA-fragment-linear layout ----------------
// packed[((nf*64 + kt)*64 + lane)*16 + b] = W[nf*16 + (lane&15)][kt*64 + (lane>>4)*16 + b]
// so a B-fragment for mfma_i32_16x16x64 is one coalesced global_load_dwordx4 at
// base + lane*16 (1 KB/instr) -> weights never touch LDS in the GEMMs.
__global__ __launch_bounds__(256) void pack_frag_kernel(
    const int* __restrict__ s0, const int* __restrict__ s1,
    const int* __restrict__ s2, const int* __restrict__ s3,
    signed char* __restrict__ d0, signed char* __restrict__ d1,
    signed char* __restrict__ d2, signed char* __restrict__ d3)
{
    int g = blockIdx.x * 256 + threadIdx.x;    // 4 * 2^20 threads
    int which = g >> 20;
    int u = g & 0xFFFFF;
    int n  = u >> 8;                           // 0..4095 (coalesced src rows)
    int kc = u & 255;                          // 16B chunk within row
    const int* src = (which == 0) ? s0 : (which == 1) ? s1 : (which == 2) ? s2 : s3;
    signed char* dst = (which == 0) ? d0 : (which == 1) ? d1 : (which == 2) ? d2 : d3;

    const int4* sp = (const int4*)(src + (size_t)n * HID + kc * 16);
    union { signed char c[16]; int4 v; } out;
    #pragma unroll
    for (int q = 0; q < 4; q++) {
        int4 v = sp[q];
        out.c[4 * q + 0] = (signed char)v.x;
        out.c[4 * q + 1] = (signed char)v.y;
        out.c[4 * q + 2] = (signed char)v.z;
        out.c[4 * q + 3] = (signed char)v.w;
    }
    int nf = n >> 4, kt = kc >> 2, ln = (kc & 3) * 16 + (n & 15);
    ((int4*)dst)[(size_t)(nf * 64 + kt) * 64 + ln] = out.v;
}

// ---------------- quantize hidden_states ----------------
__global__ __launch_bounds__(256) void quant_x_kernel(const float* __restrict__ src,
                                                      signed char* __restrict__ dst, int n4) {
    int i = blockIdx.x * 256 + threadIdx.x;
    if (i >= n4) return;
    float4 v = ((const float4*)src)[i];
    char4 c;
    c.x = quant_i8(v.x * 50.0f);
    c.y = quant_i8(v.y * 50.0f);
    c.z = quant_i8(v.z * 50.0f);
    c.w = quant_i8(v.w * 50.0f);
    ((char4*)dst)[i] = c;
}

// ---------------- int8 GEMM, direct-from-L2 B-fragments ----------------
// C[m,n] = A.B^T.  Block = 256 thr = 4 waves (1m x 4n), tile 128x256,
// wave output 128x64 (acc 128 VGPR).  B streams straight from global in
// frag-linear layout (no LDS, no barriers for B); only A is LDS-staged
// (8 KB/K-tile, ring-2).
// RACE FIX vs r3: every phase now ends {counted vmcnt -> s_barrier} and
// every rdA(buf) sits one barrier AFTER all waves' stages of buf retired
// (vmcnt(4) proves only the OWN wave's gload_lds done; the barrier makes
// it all-waves).  Buffer overwrite is 2 barriers after its last read.
// A swizzle: logical chunk c of row r at phys (c+r)&3 (pre-swizzled
// global source, linear LDS dest per m104); read phys (quad+r)&3.
template<bool F32OUT>
__device__ __forceinline__ void gemm_dfb(
    const signed char* __restrict__ A,        // [M][K] row-major
    const signed char* __restrict__ Bp,       // frag-packed [NF][KT][64][16]
    const void* __restrict__ bias, void* __restrict__ outp,
    int m0, int n0, int N, int K, float alpha, float beta)
{
    __shared__ __align__(16) signed char sA0[128 * 64];
    __shared__ __align__(16) signed char sA1[128 * 64];

    const int t    = threadIdx.x;             // 0..255
    const int w    = t >> 6;                  // 0..3 (n-wave)
    const int lane = t & 63;
    const int lm   = lane & 15;
    const int quad = lane >> 4;
    const int KT   = K >> 6;                  // 64-byte K-tiles (even)

    // A staging source (pre-swizzled chunk), 2 gload_lds16 per thread
    const int r0 = t >> 2,          c0 = ((t & 3) - r0) & 3;
    const int r1 = (t + 256) >> 2,  c1 = (((t + 256) & 3) - r1) & 3;
    const signed char* aSrc0 = A + (size_t)(m0 + r0) * K + c0 * 16;
    const signed char* aSrc1 = A + (size_t)(m0 + r1) * K + c1 * 16;

    // B fragment base for this wave: nf = n0/16 + w*4 + j
    const size_t jstride = (size_t)KT * 1024;
    const signed char* bBase = Bp + (size_t)((n0 >> 4) + w * 4) * jstride + (size_t)lane * 16;

    v4i acc[8][4] = {};
    v4i bfA[4], bfB[4], af[8];

    auto stageA = [&](signed char* dst, int kt) {
        GLOAD_LDS16(aSrc0 + kt * 64, dst + t * 16);
        GLOAD_LDS16(aSrc1 + kt * 64, dst + (t + 256) * 16);
    };
    auto loadB = [&](v4i* bf, int kt) {
        const signed char* p = bBase + (size_t)kt * 1024;
        #pragma unroll
        for (int j = 0; j < 4; j++) bf[j] = *(const v4i*)(p + (size_t)j * jstride);
    };
    auto rdA = [&](const signed char* slot) {
        #pragma unroll
        for (int i = 0; i < 8; i++) {
            int r = 16 * i + lm;
            af[i] = *(const v4i*)(slot + r * 64 + (((r + quad) & 3) << 4));
        }
    };

    // prologue: stage kt=0 (A->sA0) + load B0; vmcnt(4) retires the 2 A-stages
    // (4 B-loads stay in flight), barrier makes kt=0 staging all-waves visible.
    stageA(sA0, 0);
    __builtin_amdgcn_sched_barrier(0);        // keep A-stages oldest in vmcnt order
    loadB(bfA, 0);
    asm volatile("s_waitcnt vmcnt(4)" ::: "memory");
    __builtin_amdgcn_s_barrier();

    for (int kt = 0; kt < KT; kt += 2) {
        // ---- even: prefetch kt+1 -> sA1/bfB; compute kt from sA0/bfA
        stageA(sA1, kt + 1);                  // kt+1 <= KT-1 always (KT even)
        __builtin_amdgcn_sched_barrier(0);
        loadB(bfB, kt + 1);
        __builtin_amdgcn_sched_barrier(0);
        rdA(sA0);                             // reg dep -> compiler waits lgkm
        __builtin_amdgcn_s_setprio(1);
        #pragma unroll
        for (int i = 0; i < 8; i++)
            #pragma unroll
            for (int j = 0; j < 4; j++)
                acc[i][j] = __builtin_amdgcn_mfma_i32_16x16x64_i8(af[i], bfA[j], acc[i][j], 0, 0, 0);
        __builtin_amdgcn_s_setprio(0);
        asm volatile("s_waitcnt vmcnt(4)" ::: "memory");  // own sA1 stages done
        __builtin_amdgcn_s_barrier();                     // all waves staged sA1

        if (kt + 2 < KT) {
            // ---- odd: prefetch kt+2 -> sA0/bfA; compute kt+1 from sA1/bfB
            stageA(sA0, kt + 2);
            __builtin_amdgcn_sched_barrier(0);
            loadB(bfA, kt + 2);
            __builtin_amdgcn_sched_barrier(0);
            rdA(sA1);
            __builtin_amdgcn_s_setprio(1);
            #pragma unroll
            for (int i = 0; i < 8; i++)
                #pragma unroll
                for (int j = 0; j < 4; j++)
                    acc[i][j] = __builtin_amdgcn_mfma_i32_16x16x64_i8(af[i], bfB[j], acc[i][j], 0, 0, 0);
            __builtin_amdgcn_s_setprio(0);
            asm volatile("s_waitcnt vmcnt(4)" ::: "memory");
            __builtin_amdgcn_s_barrier();
        } else {
            // ---- final odd phase: nothing left to prefetch
            rdA(sA1);
            __builtin_amdgcn_s_setprio(1);
            #pragma unroll
            for (int i = 0; i < 8; i++)
                #pragma unroll
                for (int j = 0; j < 4; j++)
                    acc[i][j] = __builtin_amdgcn_mfma_i32_16x16x64_i8(af[i], bfB[j], acc[i][j], 0, 0, 0);
            __builtin_amdgcn_s_setprio(0);
        }
    }

    // epilogue: C layout col=lm, row=quad*4+reg (verified r0-r2)
    const int orow = quad * 4;
    #pragma unroll
    for (int i = 0; i < 8; i++) {
        #pragma unroll
        for (int j = 0; j < 4; j++) {
            #pragma unroll
            for (int r = 0; r < 4; r++) {
                int row = m0 + 16 * i + orow + r;
                int col = n0 + w * 64 + 16 * j + lm;
                float v = (float)acc[i][j][r];
                if (F32OUT) {
                    ((float*)outp)[(size_t)row * N + col] = v * alpha + ((const float*)bias)[col];
                } else {
                    float q = v * alpha + (float)((const int*)bias)[col] * beta;
                    ((signed char*)outp)[(size_t)row * N + col] = quant_i8(q);
                }
            }
        }
    }
}

// fused Q/K/V: 16 m-tiles x 48 n-panels = 768 blocks, 2/CU.
// XCD chunking: 48 n-panels = 8 XCD x 6; m fastest within a panel so the
// two co-resident blocks on a CU share the same B-panel (L1/L2-hot).
__global__ __launch_bounds__(256, 2) void gemm_qkv(
    const signed char* __restrict__ x8,
    const signed char* __restrict__ wq, const signed char* __restrict__ wk,
    const signed char* __restrict__ wv,
    const int* __restrict__ bq, const int* __restrict__ bk, const int* __restrict__ bv,
    signed char* __restrict__ q8, signed char* __restrict__ k8, signed char* __restrict__ v8)
{
    const int id  = blockIdx.x;               // 0..767
    const int xcd = id & 7;
    const int j   = id >> 3;                  // 0..95
    const int nb  = xcd * 6 + (j >> 4);       // 0..47
    const int mt  = j & 15;
    const int which = nb >> 4;
    const int n0  = (nb & 15) * 256;
    const signed char* Bw = (which == 0) ? wq : (which == 1) ? wk : wv;
    const int* bias = (which == 0) ? bq : (which == 1) ? bk : bv;
    signed char* outp = (which == 0) ? q8 : (which == 1) ? k8 : v8;
    gemm_dfb<false>(x8, Bw, bias, outp, mt * 128, n0, HID, HID, 0.004f, 2.0f);
}

// o-proj: 16 m x 16 n = 256 blocks (same XCD chunking, 16 = 8x2)
__global__ __launch_bounds__(256, 2) void gemm_o(
    const signed char* __restrict__ c8, const signed char* __restrict__ wo,
    const float* __restrict__ bo, float* __restrict__ outp)
{
    const int id  = blockIdx.x;               // 0..255
    const int xcd = id & 7;
    const int j   = id >> 3;                  // 0..31
    const int nb  = xcd * 2 + (j >> 4);       // 0..15
    const int mt  = j & 15;
    gemm_dfb<true>(c8, wo, bo, outp, mt * 128, nb * 256, HID, HID, 0.0005f, 0.0f);
}

// ---------------- RoPE (in-place on q,k) + V transpose (8 s-rows/thread) ----------------
__global__ __launch_bounds__(128) void rope_kernel(
    const int* __restrict__ pos_ids, signed char* __restrict__ q,
    signed char* __restrict__ k, const signed char* __restrict__ v,
    signed char* __restrict__ vt)
{
    const int bid = blockIdx.x;
    const int sg = bid & 127;
    const int h  = (bid >> 7) & (NH - 1);
    const int b  = bid >> 12;
    const int d  = threadIdx.x;
    const int s0 = sg * 8;
    const int bh = b * NH + h;

    float inv = expf(-(float)(2 * (d & 63)) * (9.210340371976184f / 128.0f));

    float qd[8], qp[8], kd[8], kp[8];
    signed char vd[8];
    int pos[8];
    size_t base[8];
    #pragma unroll
    for (int i = 0; i < 8; i++) {
        int s = s0 + i;
        base[i] = ((size_t)(b * SEQ + s) * NH + h) * (size_t)HD;
        pos[i] = pos_ids[b * SEQ + s];
        qd[i] = (float)q[base[i] + d];
        qp[i] = (float)q[base[i] + (d ^ 64)];
        kd[i] = (float)k[base[i] + d];
        kp[i] = (float)k[base[i] + (d ^ 64)];
        vd[i] = v[base[i] + d];
    }
    __syncthreads();

    union { signed char c[8]; int2 i2; } vu;
    #pragma unroll
    for (int i = 0; i < 8; i++) {
        float freq = (float)pos[i] * inv;
        float cs, sn;
        __sincosf(freq, &sn, &cs);
        float rotq = (d < 64) ? -qp[i] : qp[i];
        float rotk = (d < 64) ? -kp[i] : kp[i];
        q[base[i] + d] = quant_i8(qd[i] * cs + rotq * sn);
        k[base[i] + d] = quant_i8(kd[i] * cs + rotk * sn);
        vu.c[i] = vd[i];
    }
    *(int2*)(vt + ((size_t)(bh * HD + d)) * SEQ + s0) = vu.i2;
}

// ---------------- attention: 32 q-rows/block, K/V frags reused for 2 row-sets ----------------
__global__ __launch_bounds__(256) void attn_kernel(
    const signed char* __restrict__ q, const signed char* __restrict__ k,
    const signed char* __restrict__ vt, signed char* __restrict__ ctx)
{
    __shared__ __align__(16) signed char p8[32 * 1040];
    __shared__ float red[128];

    const int w    = threadIdx.x >> 6;
    const int lane = threadIdx.x & 63;
    const int bid  = blockIdx.x;
    const int mt   = bid & 31;
    const int bh   = bid >> 5;
    const int b    = bh >> 5, h = bh & 31;
    const int m0   = mt * 32;
    const int lm   = lane & 15;
    const int quad = lane >> 4;

    const float SCALE = 0.0025f / 11.313708498984761f;  // S_Q*S_K/sqrt(HD)
    const float LOG2E = 1.4426950408889634f;

    const signed char* qb_base = q + ((size_t)(b * SEQ + m0 + lm) * NH + h) * (size_t)HD + quad * 16;
    v4i qb0 = *(const v4i*)qb_base;
    v4i qb1 = *(const v4i*)(qb_base + 64);
    const signed char* qb_base2 = qb_base + (size_t)16 * NH * HD;
    v4i qb2 = *(const v4i*)qb_base2;
    v4i qb3 = *(const v4i*)(qb_base2 + 64);

    float vals0[16][4], vals1[16][4];
    #pragma unroll
    for (int j = 0; j < 16; j++) {
        int t0 = w * 256 + j * 16;
        const signed char* kb = k + ((size_t)(b * SEQ + t0 + lm) * NH + h) * (size_t)HD + quad * 16;
        v4i a0 = *(const v4i*)kb;
        v4i a1 = *(const v4i*)(kb + 64);
        v4i acc0 = {}, acc1 = {};
        __builtin_amdgcn_s_setprio(1);
        acc0 = __builtin_amdgcn_mfma_i32_16x16x64_i8(a0, qb0, acc0, 0, 0, 0);
        acc0 = __builtin_amdgcn_mfma_i32_16x16x64_i8(a1, qb1, acc0, 0, 0, 0);
        acc1 = __builtin_amdgcn_mfma_i32_16x16x64_i8(a0, qb2, acc1, 0, 0, 0);
        acc1 = __builtin_amdgcn_mfma_i32_16x16x64_i8(a1, qb3, acc1, 0, 0, 0);
        __builtin_amdgcn_s_setprio(0);
        #pragma unroll
        for (int r = 0; r < 4; r++) {
            vals0[j][r] = (float)acc0[r] * SCALE;
            vals1[j][r] = (float)acc1[r] * SCALE;
        }
    }

    float mx0 = vals0[0][0], mx1 = vals1[0][0];
    #pragma unroll
    for (int j = 0; j < 16; j++)
        #pragma unroll
        for (int r = 0; r < 4; r++) {
            mx0 = fmaxf(mx0, vals0[j][r]);
            mx1 = fmaxf(mx1, vals1[j][r]);
        }
    mx0 = fmaxf(mx0, __shfl_xor(mx0, 16)); mx0 = fmaxf(mx0, __shfl_xor(mx0, 32));
    mx1 = fmaxf(mx1, __shfl_xor(mx1, 16)); mx1 = fmaxf(mx1, __shfl_xor(mx1, 32));
    if (lane < 16) { red[w * 16 + lane] = mx0; red[64 + w * 16 + lane] = mx1; }
    __syncthreads();
    mx0 = fmaxf(fmaxf(red[lm], red[16 + lm]), fmaxf(red[32 + lm], red[48 + lm]));
    mx1 = fmaxf(fmaxf(red[64 + lm], red[80 + lm]), fmaxf(red[96 + lm], red[112 + lm]));

    float sum0 = 0.f, sum1 = 0.f;
    #pragma unroll
    for (int j = 0; j < 16; j++)
        #pragma unroll
        for (int r = 0; r < 4; r++) {
            vals0[j][r] = exp2f((vals0[j][r] - mx0) * LOG2E); sum0 += vals0[j][r];
            vals1[j][r] = exp2f((vals1[j][r] - mx1) * LOG2E); sum1 += vals1[j][r];
        }
    sum0 += __shfl_xor(sum0, 16); sum0 += __shfl_xor(sum0, 32);
    sum1 += __shfl_xor(sum1, 16); sum1 += __shfl_xor(sum1, 32);
    __syncthreads();
    if (lane < 16) { red[w * 16 + lane] = sum0; red[64 + w * 16 + lane] = sum1; }
    __syncthreads();
    sum0 = (red[lm] + red[16 + lm]) + (red[32 + lm] + red[48 + lm]);
    sum1 = (red[64 + lm] + red[80 + lm]) + (red[96 + lm] + red[112 + lm]);
    float sf0 = 127.0f / sum0, sf1 = 127.0f / sum1;

    #pragma unroll
    for (int j = 0; j < 16; j++) {
        union { signed char cc[4]; int ii; } u0, u1;
        #pragma unroll
        for (int r = 0; r < 4; r++) {
            u0.cc[r] = quant_i8(vals0[j][r] * sf0);
            u1.cc[r] = quant_i8(vals1[j][r] * sf1);
        }
        int ch = (((w * 16 + j) + 4 * lm) & 63) * 16 + quad * 4;
        *(int*)(p8 + lm * 1040 + ch) = u0.ii;
        *(int*)(p8 + (16 + lm) * 1040 + ch) = u1.ii;
    }
    __syncthreads();

    v4i accp0[2] = {}, accp1[2] = {};
    for (int kk = 0; kk < SEQ; kk += 64) {
        int ph = (((kk >> 4) + quad) + 4 * lm) & 63;
        v4i af0 = *(const v4i*)(p8 + lm * 1040 + ph * 16);
        v4i af1 = *(const v4i*)(p8 + (16 + lm) * 1040 + ph * 16);
        v4i vb0 = *(const v4i*)(vt + ((size_t)(bh * HD + w * 32 + lm)) * (size_t)SEQ + kk + quad * 16);
        v4i vb1 = *(const v4i*)(vt + ((size_t)(bh * HD + w * 32 + 16 + lm)) * (size_t)SEQ + kk + quad * 16);
        __builtin_amdgcn_s_setprio(1);
        accp0[0] = __builtin_amdgcn_mfma_i32_16x16x64_i8(af0, vb0, accp0[0], 0, 0, 0);
        accp1[0] = __builtin_amdgcn_mfma_i32_16x16x64_i8(af1, vb0, accp1[0], 0, 0, 0);
        accp0[1] = __builtin_amdgcn_mfma_i32_16x16x64_i8(af0, vb1, accp0[1], 0, 0, 0);
        accp1[1] = __builtin_amdgcn_mfma_i32_16x16x64_i8(af1, vb1, accp1[1], 0, 0, 0);
        __builtin_amdgcn_s_setprio(0);
    }
    #pragma unroll
    for (int j = 0; j < 2; j++) {
        #pragma unroll
        for (int r = 0; r < 4; r++) {
            int row = quad * 4 + r;
            int col = w * 32 + j * 16 + lm;
            ctx[((size_t)(b * SEQ + m0 + row) * NH + h) * (size_t)HD + col] =
                quant_i8((float)accp0[j][r] * (1.0f / 127.0f));
            ctx[((size_t)(b * SEQ + m0 + 16 + row) * NH + h) * (size_t)HD + col] =
                quant_i8((float)accp1[j][r] * (1.0f / 127.0f));
        }
    }
}

// ---------------- launch ----------------
extern "C" void kernel_launch(void* const* d_in, const int* in_sizes, int n_in,
                              void* d_out, int out_size, void* d_ws, size_t ws_size,
                              hipStream_t stream)
{
    const float* hidden = (const float*)d_in[0];
    const int* pos_ids  = (const int*)d_in[1];
    const int* w_q = (const int*)d_in[2];
    const int* w_k = (const int*)d_in[3];
    const int* w_v = (const int*)d_in[4];
    const int* w_o = (const int*)d_in[5];
    const int* b_q = (const int*)d_in[6];
    const int* b_k = (const int*)d_in[7];
    const int* b_v = (const int*)d_in[8];
    const float* b_o = (const float*)d_in[9];
    float* out = (float*)d_out;

    char* ws = (char*)d_ws;
    const size_t WSZ = (size_t)HID * HID;
    signed char* wq8 = (signed char*)ws;
    signed char* wk8 = wq8 + WSZ;
    signed char* wv8 = wk8 + WSZ;
    signed char* wo8 = wv8 + WSZ;
    signed char* x8  = wo8 + WSZ;
    const size_t ASZ = (size_t)BB * SEQ * HID;
    signed char* q8  = x8 + ASZ;
    signed char* k8  = q8 + ASZ;
    signed char* v8  = k8 + ASZ;
    signed char* vt8 = v8 + ASZ;
    signed char* c8  = vt8 + ASZ;

    pack_frag_kernel<<<4 * (1 << 20) / 256, 256, 0, stream>>>(w_q, w_k, w_v, w_o,
                                                              wq8, wk8, wv8, wo8);
    int xn4 = (int)(ASZ / 4);
    quant_x_kernel<<<xn4 / 256, 256, 0, stream>>>(hidden, x8, xn4);

    gemm_qkv<<<768, 256, 0, stream>>>(x8, wq8, wk8, wv8, b_q, b_k, b_v,
                                      q8, k8, v8);

    rope_kernel<<<BB * NH * (SEQ / 8), 128, 0, stream>>>(pos_ids, q8, k8, v8, vt8);
    attn_kernel<<<BB * NH * (SEQ / 32), 256, 0, stream>>>(q8, k8, vt8, c8);

    gemm_o<<<256, 256, 0, stream>>>(c8, wo8, b_o, out);
}

// Round 7
// 549.001 us; speedup vs baseline: 1.7981x; 1.7981x over previous
//
#include <hip/hip_runtime.h>
#include <hip/hip_bf16.h>
#include <cstdint>
#include <cstddef>

typedef int v4i __attribute__((ext_vector_type(4)));

#define NH 32
#define HD 128
#define SEQ 1024
#define HID 4096
#define BB 2

__device__ __forceinline__ signed char quant_i8(float x) {
    float r = rintf(x);                       // round-half-to-even, matches jnp.round
    r = fminf(fmaxf(r, -128.0f), 127.0f);
    return (signed char)r;
}

#define GLOAD_LDS16(g, l) \
    __builtin_amdgcn_global_load_lds((const __attribute__((address_space(1))) void*)(g), \
                                     (__attribute__((address_space(3))) void*)(l), 16, 0, 0)

// ---------------- pack int32 -> int8 (all 4 weights in one launch) ----------------
__global__ __launch_bounds__(256) void pack4_i8_kernel(
    const int* __restrict__ s0, const int* __restrict__ s1,
    const int* __restrict__ s2, const int* __restrict__ s3,
    signed char* __restrict__ d0, signed char* __restrict__ d1,
    signed char* __restrict__ d2, signed char* __restrict__ d3, int n4)
{
    int i = blockIdx.x * 256 + threadIdx.x;
    int which = i >> 22;                  // n4 = HID*HID/4 = 2^22
    int idx = i & ((1 << 22) - 1);
    const int* src = (which == 0) ? s0 : (which == 1) ? s1 : (which == 2) ? s2 : s3;
    signed char* dst = (which == 0) ? d0 : (which == 1) ? d1 : (which == 2) ? d2 : d3;
    int4 v = ((const int4*)src)[idx];
    char4 c;
    c.x = (signed char)v.x; c.y = (signed char)v.y;
    c.z = (signed char)v.z; c.w = (signed char)v.w;
    ((char4*)dst)[idx] = c;
}

// ---------------- quantize hidden_states ----------------
__global__ __launch_bounds__(256) void quant_x_kernel(const float* __restrict__ src,
                                                      signed char* __restrict__ dst, int n4) {
    int i = blockIdx.x * 256 + threadIdx.x;
    if (i >= n4) return;
    float4 v = ((const float4*)src)[i];
    char4 c;
    c.x = quant_i8(v.x * 50.0f);
    c.y = quant_i8(v.y * 50.0f);
    c.z = quant_i8(v.z * 50.0f);
    c.w = quant_i8(v.w * 50.0f);
    ((char4*)dst)[i] = c;
}

// ---------------- int8 GEMM, TLP-overlap core: C[m,n] = A.B^T ----------------
// 128x128 tile, BK=64B, 256 thr = 4 waves (2x2), wave tile 64x64 (acc 64 VGPR).
// LDS = ring-2 x (8KB A + 8KB B) = 32 KB -> 4 independent blocks/CU (16 waves).
// The r0-r2 invariant (~30% MfmaUtil) was barrier-lockstep: all resident waves
// ds_read together (matrix idle) then MFMA together (LDS idle). With 4
// UNSYNCHRONIZED blocks/CU, one block's MFMA phase covers the others'
// staging/barrier stalls -- overlap by TLP, no fragile hand-scheduling.
// Proven-correct r0 sync pattern kept verbatim (__syncthreads = full drain,
// stage(next) issued right after so the drain overlaps this iter's MFMA).
// Swizzle (BK=64): logical 16B-chunk c of row r at phys (c + (r>>1)) & 3
// (row>>1, NOT row: row stride 64B = 16 banks, row parity already splits
// banks, so slot must advance every 2 rows). Read slot (quad+(r>>1))&3 ->
// 16-lane group covers all 32 banks 2-way = free (m136). r4's (c+r)&3 at
// BK=64 was 4-way (6.3M conflicts measured).
template<bool F32OUT>
__device__ __forceinline__ void gemm128(
    const signed char* __restrict__ A, const signed char* __restrict__ Bw,
    const void* __restrict__ bias, void* __restrict__ outp,
    int m0, int n0, int N, int K, float alpha, float beta)
{
    __shared__ __align__(16) signed char sA[2][128 * 64];
    __shared__ __align__(16) signed char sB[2][128 * 64];

    const int t    = threadIdx.x;
    const int w    = t >> 6;
    const int lane = t & 63;
    const int lm   = lane & 15;
    const int quad = lane >> 4;
    const int wm   = (w >> 1) * 64;
    const int wn   = (w & 1) * 64;

    // staging map (pre-swizzled global source, linear LDS dest per m104)
    int row0 = t >> 2,          cc0 = ((t & 3) - (row0 >> 1)) & 3;
    int row1 = (t + 256) >> 2,  cc1 = (((t + 256) & 3) - (row1 >> 1)) & 3;
    const signed char* aS0 = A  + (size_t)(m0 + row0) * K + cc0 * 16;
    const signed char* aS1 = A  + (size_t)(m0 + row1) * K + cc1 * 16;
    const signed char* bS0 = Bw + (size_t)(n0 + row0) * K + cc0 * 16;
    const signed char* bS1 = Bw + (size_t)(n0 + row1) * K + cc1 * 16;

    v4i acc[4][4] = {};

    // prologue: stage buffer 0 @ k0=0
    GLOAD_LDS16(aS0, &sA[0][t * 16]);
    GLOAD_LDS16(aS1, &sA[0][(t + 256) * 16]);
    GLOAD_LDS16(bS0, &sB[0][t * 16]);
    GLOAD_LDS16(bS1, &sB[0][(t + 256) * 16]);

    // frag read slot is i/j-independent: (quad + (row>>1))&3 with row=wm+16i+lm
    // reduces to (quad + ((wm>>1) + (lm>>1)))&3  (16i contributes 8i === 0 mod 4)
    const int aslot = ((quad + (wm >> 1) + (lm >> 1)) & 3) << 4;
    const int bslot = ((quad + (wn >> 1) + (lm >> 1)) & 3) << 4;

    int buf = 0;
    for (int k0 = 0; k0 < K; k0 += 64) {
        __syncthreads();   // publish buf (vmcnt drain overlapped w/ prev MFMA)
        if (k0 + 64 < K) {
            int nb = buf ^ 1;
            GLOAD_LDS16(aS0 + k0 + 64, &sA[nb][t * 16]);
            GLOAD_LDS16(aS1 + k0 + 64, &sA[nb][(t + 256) * 16]);
            GLOAD_LDS16(bS0 + k0 + 64, &sB[nb][t * 16]);
            GLOAD_LDS16(bS1 + k0 + 64, &sB[nb][(t + 256) * 16]);
        }
        v4i af[4], bf[4];
        #pragma unroll
        for (int i = 0; i < 4; i++)
            af[i] = *(const v4i*)(&sA[buf][(wm + 16 * i + lm) * 64 + aslot]);
        #pragma unroll
        for (int j = 0; j < 4; j++)
            bf[j] = *(const v4i*)(&sB[buf][(wn + 16 * j + lm) * 64 + bslot]);
        __builtin_amdgcn_s_setprio(1);
        #pragma unroll
        for (int i = 0; i < 4; i++)
            #pragma unroll
            for (int j = 0; j < 4; j++)
                acc[i][j] = __builtin_amdgcn_mfma_i32_16x16x64_i8(af[i], bf[j], acc[i][j], 0, 0, 0);
        __builtin_amdgcn_s_setprio(0);
        buf ^= 1;
    }

    // epilogue: C layout col=lm, row=quad*4+reg (verified r0-r2)
    const int orow = quad * 4;
    #pragma unroll
    for (int i = 0; i < 4; i++) {
        #pragma unroll
        for (int j = 0; j < 4; j++) {
            #pragma unroll
            for (int r = 0; r < 4; r++) {
                int row = m0 + wm + 16 * i + orow + r;
                int col = n0 + wn + 16 * j + lm;
                float v = (float)acc[i][j][r];
                if (F32OUT) {
                    ((float*)outp)[(size_t)row * N + col] = v * alpha + ((const float*)bias)[col];
                } else {
                    float q = v * alpha + (float)((const int*)bias)[col] * beta;
                    ((signed char*)outp)[(size_t)row * N + col] = quant_i8(q);
                }
            }
        }
    }
}

// fused Q/K/V projection (r0-proven mapping: consecutive x-blocks share A-panel)
__global__ __launch_bounds__(256, 4) void gemm_qkv(
    const signed char* __restrict__ x8,
    const signed char* __restrict__ wq, const signed char* __restrict__ wk,
    const signed char* __restrict__ wv,
    const int* __restrict__ bq, const int* __restrict__ bk, const int* __restrict__ bv,
    signed char* __restrict__ q8, signed char* __restrict__ k8, signed char* __restrict__ v8)
{
    const int nblk = blockIdx.x;          // 0..95
    const int which = nblk >> 5;
    const int n0 = (nblk & 31) * 128;
    const int m0 = blockIdx.y * 128;      // 0..15 -> M=2048
    const signed char* Bw = (which == 0) ? wq : (which == 1) ? wk : wv;
    const int* bias = (which == 0) ? bq : (which == 1) ? bk : bv;
    signed char* outp = (which == 0) ? q8 : (which == 1) ? k8 : v8;
    gemm128<false>(x8, Bw, bias, outp, m0, n0, HID, HID, 0.004f, 2.0f);
}

// o-proj: M = BB*SEQ = 2048 -> 16 m-tiles (grid dim3(32,16); r5's dim3(32,32)
// wrote rows up to 4095 into a 2048-row output = OOB fault, the r6 core dump)
__global__ __launch_bounds__(256, 4) void gemm_o(
    const signed char* __restrict__ c8, const signed char* __restrict__ wo,
    const float* __restrict__ bo, float* __restrict__ outp)
{
    gemm128<true>(c8, wo, bo, outp, blockIdx.y * 128, blockIdx.x * 128,
                  HID, HID, 0.0005f, 0.0f);
}

// ---------------- RoPE (in-place on q,k) + V transpose (8 s-rows/thread) ----------------
__global__ __launch_bounds__(128) void rope_kernel(
    const int* __restrict__ pos_ids, signed char* __restrict__ q,
    signed char* __restrict__ k, const signed char* __restrict__ v,
    signed char* __restrict__ vt)
{
    const int bid = blockIdx.x;
    const int sg = bid & 127;
    const int h  = (bid >> 7) & (NH - 1);
    const int b  = bid >> 12;
    const int d  = threadIdx.x;
    const int s0 = sg * 8;
    const int bh = b * NH + h;

    float inv = expf(-(float)(2 * (d & 63)) * (9.210340371976184f / 128.0f));

    float qd[8], qp[8], kd[8], kp[8];
    signed char vd[8];
    int pos[8];
    size_t base[8];
    #pragma unroll
    for (int i = 0; i < 8; i++) {
        int s = s0 + i;
        base[i] = ((size_t)(b * SEQ + s) * NH + h) * (size_t)HD;
        pos[i] = pos_ids[b * SEQ + s];
        qd[i] = (float)q[base[i] + d];
        qp[i] = (float)q[base[i] + (d ^ 64)];
        kd[i] = (float)k[base[i] + d];
        kp[i] = (float)k[base[i] + (d ^ 64)];
        vd[i] = v[base[i] + d];
    }
    __syncthreads();

    union { signed char c[8]; int2 i2; } vu;
    #pragma unroll
    for (int i = 0; i < 8; i++) {
        float freq = (float)pos[i] * inv;
        float cs, sn;
        __sincosf(freq, &sn, &cs);
        float rotq = (d < 64) ? -qp[i] : qp[i];
        float rotk = (d < 64) ? -kp[i] : kp[i];
        q[base[i] + d] = quant_i8(qd[i] * cs + rotq * sn);
        k[base[i] + d] = quant_i8(kd[i] * cs + rotk * sn);
        vu.c[i] = vd[i];
    }
    *(int2*)(vt + ((size_t)(bh * HD + d)) * SEQ + s0) = vu.i2;
}

// ---------------- attention: 32 q-rows/block, K/V frags reused for 2 row-sets ----------------
__global__ __launch_bounds__(256) void attn_kernel(
    const signed char* __restrict__ q, const signed char* __restrict__ k,
    const signed char* __restrict__ vt, signed char* __restrict__ ctx)
{
    __shared__ __align__(16) signed char p8[32 * 1040];
    __shared__ float red[128];

    const int w    = threadIdx.x >> 6;
    const int lane = threadIdx.x & 63;
    const int bid  = blockIdx.x;
    const int mt   = bid & 31;
    const int bh   = bid >> 5;
    const int b    = bh >> 5, h = bh & 31;
    const int m0   = mt * 32;
    const int lm   = lane & 15;
    const int quad = lane >> 4;

    const float SCALE = 0.0025f / 11.313708498984761f;  // S_Q*S_K/sqrt(HD)
    const float LOG2E = 1.4426950408889634f;

    const signed char* qb_base = q + ((size_t)(b * SEQ + m0 + lm) * NH + h) * (size_t)HD + quad * 16;
    v4i qb0 = *(const v4i*)qb_base;
    v4i qb1 = *(const v4i*)(qb_base + 64);
    const signed char* qb_base2 = qb_base + (size_t)16 * NH * HD;
    v4i qb2 = *(const v4i*)qb_base2;
    v4i qb3 = *(const v4i*)(qb_base2 + 64);

    float vals0[16][4], vals1[16][4];
    #pragma unroll
    for (int j = 0; j < 16; j++) {
        int t0 = w * 256 + j * 16;
        const signed char* kb = k + ((size_t)(b * SEQ + t0 + lm) * NH + h) * (size_t)HD + quad * 16;
        v4i a0 = *(const v4i*)kb;
        v4i a1 = *(const v4i*)(kb + 64);
        v4i acc0 = {}, acc1 = {};
        __builtin_amdgcn_s_setprio(1);
        acc0 = __builtin_amdgcn_mfma_i32_16x16x64_i8(a0, qb0, acc0, 0, 0, 0);
        acc0 = __builtin_amdgcn_mfma_i32_16x16x64_i8(a1, qb1, acc0, 0, 0, 0);
        acc1 = __builtin_amdgcn_mfma_i32_16x16x64_i8(a0, qb2, acc1, 0, 0, 0);
        acc1 = __builtin_amdgcn_mfma_i32_16x16x64_i8(a1, qb3, acc1, 0, 0, 0);
        __builtin_amdgcn_s_setprio(0);
        #pragma unroll
        for (int r = 0; r < 4; r++) {
            vals0[j][r] = (float)acc0[r] * SCALE;
            vals1[j][r] = (float)acc1[r] * SCALE;
        }
    }

    float mx0 = vals0[0][0], mx1 = vals1[0][0];
    #pragma unroll
    for (int j = 0; j < 16; j++)
        #pragma unroll
        for (int r = 0; r < 4; r++) {
            mx0 = fmaxf(mx0, vals0[j][r]);
            mx1 = fmaxf(mx1, vals1[j][r]);
        }
    mx0 = fmaxf(mx0, __shfl_xor(mx0, 16)); mx0 = fmaxf(mx0, __shfl_xor(mx0, 32));
    mx1 = fmaxf(mx1, __shfl_xor(mx1, 16)); mx1 = fmaxf(mx1, __shfl_xor(mx1, 32));
    if (lane < 16) { red[w * 16 + lane] = mx0; red[64 + w * 16 + lane] = mx1; }
    __syncthreads();
    mx0 = fmaxf(fmaxf(red[lm], red[16 + lm]), fmaxf(red[32 + lm], red[48 + lm]));
    mx1 = fmaxf(fmaxf(red[64 + lm], red[80 + lm]), fmaxf(red[96 + lm], red[112 + lm]));

    float sum0 = 0.f, sum1 = 0.f;
    #pragma unroll
    for (int j = 0; j < 16; j++)
        #pragma unroll
        for (int r = 0; r < 4; r++) {
            vals0[j][r] = exp2f((vals0[j][r] - mx0) * LOG2E); sum0 += vals0[j][r];
            vals1[j][r] = exp2f((vals1[j][r] - mx1) * LOG2E); sum1 += vals1[j][r];
        }
    sum0 += __shfl_xor(sum0, 16); sum0 += __shfl_xor(sum0, 32);
    sum1 += __shfl_xor(sum1, 16); sum1 += __shfl_xor(sum1, 32);
    __syncthreads();
    if (lane < 16) { red[w * 16 + lane] = sum0; red[64 + w * 16 + lane] = sum1; }
    __syncthreads();
    sum0 = (red[lm] + red[16 + lm]) + (red[32 + lm] + red[48 + lm]);
    sum1 = (red[64 + lm] + red[80 + lm]) + (red[96 + lm] + red[112 + lm]);
    float sf0 = 127.0f / sum0, sf1 = 127.0f / sum1;

    #pragma unroll
    for (int j = 0; j < 16; j++) {
        union { signed char cc[4]; int ii; } u0, u1;
        #pragma unroll
        for (int r = 0; r < 4; r++) {
            u0.cc[r] = quant_i8(vals0[j][r] * sf0);
            u1.cc[r] = quant_i8(vals1[j][r] * sf1);
        }
        int ch = (((w * 16 + j) + 4 * lm) & 63) * 16 + quad * 4;
        *(int*)(p8 + lm * 1040 + ch) = u0.ii;
        *(int*)(p8 + (16 + lm) * 1040 + ch) = u1.ii;
    }
    __syncthreads();

    v4i accp0[2] = {}, accp1[2] = {};
    for (int kk = 0; kk < SEQ; kk += 64) {
        int ph = (((kk >> 4) + quad) + 4 * lm) & 63;
        v4i af0 = *(const v4i*)(p8 + lm * 1040 + ph * 16);
        v4i af1 = *(const v4i*)(p8 + (16 + lm) * 1040 + ph * 16);
        v4i vb0 = *(const v4i*)(vt + ((size_t)(bh * HD + w * 32 + lm)) * (size_t)SEQ + kk + quad * 16);
        v4i vb1 = *(const v4i*)(vt + ((size_t)(bh * HD + w * 32 + 16 + lm)) * (size_t)SEQ + kk + quad * 16);
        __builtin_amdgcn_s_setprio(1);
        accp0[0] = __builtin_amdgcn_mfma_i32_16x16x64_i8(af0, vb0, accp0[0], 0, 0, 0);
        accp1[0] = __builtin_amdgcn_mfma_i32_16x16x64_i8(af1, vb0, accp1[0], 0, 0, 0);
        accp0[1] = __builtin_amdgcn_mfma_i32_16x16x64_i8(af0, vb1, accp0[1], 0, 0, 0);
        accp1[1] = __builtin_amdgcn_mfma_i32_16x16x64_i8(af1, vb1, accp1[1], 0, 0, 0);
        __builtin_amdgcn_s_setprio(0);
    }
    #pragma unroll
    for (int j = 0; j < 2; j++) {
        #pragma unroll
        for (int r = 0; r < 4; r++) {
            int row = quad * 4 + r;
            int col = w * 32 + j * 16 + lm;
            ctx[((size_t)(b * SEQ + m0 + row) * NH + h) * (size_t)HD + col] =
                quant_i8((float)accp0[j][r] * (1.0f / 127.0f));
            ctx[((size_t)(b * SEQ + m0 + 16 + row) * NH + h) * (size_t)HD + col] =
                quant_i8((float)accp1[j][r] * (1.0f / 127.0f));
        }
    }
}

// ---------------- launch ----------------
extern "C" void kernel_launch(void* const* d_in, const int* in_sizes, int n_in,
                              void* d_out, int out_size, void* d_ws, size_t ws_size,
                              hipStream_t stream)
{
    const float* hidden = (const float*)d_in[0];
    const int* pos_ids  = (const int*)d_in[1];
    const int* w_q = (const int*)d_in[2];
    const int* w_k = (const int*)d_in[3];
    const int* w_v = (const int*)d_in[4];
    const int* w_o = (const int*)d_in[5];
    const int* b_q = (const int*)d_in[6];
    const int* b_k = (const int*)d_in[7];
    const int* b_v = (const int*)d_in[8];
    const float* b_o = (const float*)d_in[9];
    float* out = (float*)d_out;

    char* ws = (char*)d_ws;
    const size_t WSZ = (size_t)HID * HID;
    signed char* wq8 = (signed char*)ws;
    signed char* wk8 = wq8 + WSZ;
    signed char* wv8 = wk8 + WSZ;
    signed char* wo8 = wv8 + WSZ;
    signed char* x8  = wo8 + WSZ;
    const size_t ASZ = (size_t)BB * SEQ * HID;
    signed char* q8  = x8 + ASZ;
    signed char* k8  = q8 + ASZ;
    signed char* v8  = k8 + ASZ;
    signed char* vt8 = v8 + ASZ;
    signed char* c8  = vt8 + ASZ;

    int wn4 = HID * HID / 4;
    pack4_i8_kernel<<<4 * wn4 / 256, 256, 0, stream>>>(w_q, w_k, w_v, w_o,
                                                       wq8, wk8, wv8, wo8, wn4);
    int xn4 = (int)(ASZ / 4);
    quant_x_kernel<<<xn4 / 256, 256, 0, stream>>>(hidden, x8, xn4);

    gemm_qkv<<<dim3(96, 16), 256, 0, stream>>>(x8, wq8, wk8, wv8, b_q, b_k, b_v,
                                               q8, k8, v8);

    rope_kernel<<<BB * NH * (SEQ / 8), 128, 0, stream>>>(pos_ids, q8, k8, v8, vt8);
    attn_kernel<<<BB * NH * (SEQ / 32), 256, 0, stream>>>(q8, k8, vt8, c8);

    gemm_o<<<dim3(32, 16), 256, 0, stream>>>(c8, wo8, b_o, out);
}